// Round 3
// baseline (335.540 us; speedup 1.0000x reference)
//
#include <hip/hip_runtime.h>
#include <hip/hip_bf16.h>

#define NB    8192
#define NF    50
#define NE    64
#define STR   72            // LDS row stride in bf16 elems (144 B)
#define GPB   4             // batch rows per block
#define GRID  (NB / GPB)

typedef __attribute__((ext_vector_type(8))) short short8;   // 8 x bf16 MFMA A/B frag
typedef __attribute__((ext_vector_type(4))) short short4v;  // 4 x bf16 packed store
typedef __attribute__((ext_vector_type(4))) float float4v;  // MFMA C/D frag

static constexpr float SM_C   = 0.25509667991878083f; // (1/sqrt(32)) * log2(e)
static constexpr float LN_EPS = 1e-6f;

#define MFMA(a, b, c) __builtin_amdgcn_mfma_f32_16x16x32_bf16((a), (b), (c), 0, 0, 0)

__device__ __forceinline__ unsigned short f2bf(float f) {
    // native cast -> v_cvt_pk_bf16_f32 (RNE); do NOT hand-write the rounding
    return __bfloat16_as_ushort(__float2bfloat16(f));
}

__device__ __forceinline__ void st_pack4(unsigned short* p, float4v v) {
    union { unsigned short u[4]; short4v s; } r;
    r.u[0] = f2bf(v.x); r.u[1] = f2bf(v.y); r.u[2] = f2bf(v.z); r.u[3] = f2bf(v.w);
    *(short4v*)p = r.s;   // ds_write_b64
}

__device__ __forceinline__ float fexp2(float x) {
#if __has_builtin(__builtin_amdgcn_exp2f)
    return __builtin_amdgcn_exp2f(x);
#else
    float r; asm("v_exp_f32 %0, %1" : "=v"(r) : "v"(x)); return r;
#endif
}

__device__ __forceinline__ float frcp(float x) {
#if __has_builtin(__builtin_amdgcn_rcpf)
    return __builtin_amdgcn_rcpf(x);
#else
    return 1.f / x;
#endif
}

// ---- prep: transpose all weights to bf16 [mat][o][e] = W[e][o] in d_ws ----
// slots 0..7 = Wq domains, 8 = Wk, 9 = Wv, 10 = Wr
__global__ void prep_weights(const float* __restrict__ wq, const float* __restrict__ wk,
                             const float* __restrict__ wv, const float* __restrict__ wr,
                             unsigned short* __restrict__ ws) {
    int i = blockIdx.x * 256 + threadIdx.x;
    if (i >= 11 * 4096) return;
    int m = i >> 12, t = i & 4095, o = t >> 6, e = t & 63;
    float v;
    if (m < 8)       v = wq[(m * 64 + e) * 64 + o];
    else if (m == 8) v = wk[e * 64 + o];
    else if (m == 9) v = wv[e * 64 + o];
    else             v = wr[e * 64 + o];
    ws[i] = f2bf(v);
}

__global__ __launch_bounds__(256, 4)
void mdr_mfma(const float* __restrict__ x_g, const int* __restrict__ dom_g,
              const unsigned short* __restrict__ ws,
              const float* __restrict__ gam_g, const float* __restrict__ bet_g,
              float* __restrict__ out_g) {
    __shared__ __align__(16) unsigned short L[4 * NE * STR];   // 36864 B -> 4 blocks/CU
    unsigned short* Qb = L;                 // Q rowmajor [f][e]   (later: P head 1)
    unsigned short* Kb = L + NE * STR;      // K rowmajor [f][e]
    unsigned short* Vt = L + 2 * NE * STR;  // V^T [e][f]
    unsigned short* P0 = L + 3 * NE * STR;  // P head 0

    const int tid = threadIdx.x;
    const int lm  = tid & 15;        // lane & 15
    const int lg  = (tid >> 4) & 3;  // lane >> 4 within wave
    const int w   = tid >> 6;        // wave 0..3

    for (int rr = 0; rr < GPB; ++rr) {
        const int b = blockIdx.x * GPB + rr;
        __syncthreads();  // prior iteration's PV LDS reads complete
        const int dom = dom_g[b] - 1;

        // ---------------- x fragments straight from global (rows >= NF zeroed) ----------------
        const float* xb = x_g + (size_t)b * (NF * NE);
        short8 xf[4][2];
        #pragma unroll
        for (int t = 0; t < 4; ++t) {
            const int row = lm + 16 * t;
            const bool ok = row < NF;
            #pragma unroll
            for (int ks = 0; ks < 2; ++ks) {
                const int col = 8 * lg + 32 * ks;
                float4v a = {0.f, 0.f, 0.f, 0.f}, c = {0.f, 0.f, 0.f, 0.f};
                if (ok) {
                    a = *(const float4v*)(xb + row * 64 + col);
                    c = *(const float4v*)(xb + row * 64 + col + 4);
                }
                union { unsigned short u[8]; short8 s; } r;
                r.u[0] = f2bf(a.x); r.u[1] = f2bf(a.y); r.u[2] = f2bf(a.z); r.u[3] = f2bf(a.w);
                r.u[4] = f2bf(c.x); r.u[5] = f2bf(c.y); r.u[6] = f2bf(c.z); r.u[7] = f2bf(c.w);
                xf[t][ks] = r.s;
            }
        }

        // ---------------- Q^T = Wq^T x^T  (write rowmajor Q) ----------------
        {
            const unsigned short* wq = ws + dom * 4096;
            short8 qw[4][2];
            #pragma unroll
            for (int mt = 0; mt < 4; ++mt)
                #pragma unroll
                for (int ks = 0; ks < 2; ++ks)
                    qw[mt][ks] = *(const short8*)(wq + (lm + 16 * mt) * 64 + 8 * lg + 32 * ks);
            #pragma unroll
            for (int mt = 0; mt < 4; ++mt) {
                float4v acc = {0.f, 0.f, 0.f, 0.f};
                acc = MFMA(qw[mt][0], xf[w][0], acc);
                acc = MFMA(qw[mt][1], xf[w][1], acc);
                st_pack4(Qb + (lm + 16 * w) * STR + 16 * mt + 4 * lg, acc);
            }
        }
        // ---------------- K^T = Wk^T x^T  (write rowmajor K) ----------------
        {
            const unsigned short* wk = ws + 8 * 4096;
            short8 kw[4][2];
            #pragma unroll
            for (int mt = 0; mt < 4; ++mt)
                #pragma unroll
                for (int ks = 0; ks < 2; ++ks)
                    kw[mt][ks] = *(const short8*)(wk + (lm + 16 * mt) * 64 + 8 * lg + 32 * ks);
            #pragma unroll
            for (int mt = 0; mt < 4; ++mt) {
                float4v acc = {0.f, 0.f, 0.f, 0.f};
                acc = MFMA(kw[mt][0], xf[w][0], acc);
                acc = MFMA(kw[mt][1], xf[w][1], acc);
                st_pack4(Kb + (lm + 16 * w) * STR + 16 * mt + 4 * lg, acc);
            }
        }
        // ---------------- V = x Wv  (write V^T [e][f]) ----------------
        {
            const unsigned short* wv = ws + 9 * 4096;
            short8 vw[2];
            #pragma unroll
            for (int ks = 0; ks < 2; ++ks)
                vw[ks] = *(const short8*)(wv + (lm + 16 * w) * 64 + 8 * lg + 32 * ks);
            #pragma unroll
            for (int mt = 0; mt < 4; ++mt) {
                float4v acc = {0.f, 0.f, 0.f, 0.f};
                acc = MFMA(xf[mt][0], vw[0], acc);
                acc = MFMA(xf[mt][1], vw[1], acc);
                st_pack4(Vt + (lm + 16 * w) * STR + 16 * mt + 4 * lg, acc);
            }
        }
        // ---------------- R = x Wr  (registers; wave owns f-tile w) ----------------
        float4v racc[4];
        {
            const unsigned short* wr = ws + 10 * 4096;
            #pragma unroll
            for (int nt = 0; nt < 4; ++nt) {
                short8 rw0 = *(const short8*)(wr + (lm + 16 * nt) * 64 + 8 * lg);
                short8 rw1 = *(const short8*)(wr + (lm + 16 * nt) * 64 + 8 * lg + 32);
                float4v acc = {0.f, 0.f, 0.f, 0.f};
                acc = MFMA(xf[w][0], rw0, acc);
                acc = MFMA(xf[w][1], rw1, acc);
                racc[nt] = acc;
            }
        }
        __syncthreads();  // Q/K/Vt written

        // ---------------- scores: wave -> (head h, f-half fh); S^T = K Q^T ----------------
        const int h = w & 1, fh = w >> 1;
        short8 kf[4], qf[2];
        #pragma unroll
        for (int mt = 0; mt < 4; ++mt)
            kf[mt] = *(const short8*)(Kb + (lm + 16 * mt) * STR + 32 * h + 8 * lg);
        #pragma unroll
        for (int q = 0; q < 2; ++q)
            qf[q] = *(const short8*)(Qb + (lm + 16 * (2 * fh + q)) * STR + 32 * h + 8 * lg);
        __syncthreads();  // frag loads done -> safe to overwrite Qb (P1)

        float4v sacc[4][2];
        #pragma unroll
        for (int mt = 0; mt < 4; ++mt)
            #pragma unroll
            for (int q = 0; q < 2; ++q) {
                float4v z = {0.f, 0.f, 0.f, 0.f};
                sacc[mt][q] = MFMA(kf[mt], qf[q], z);
            }

        // softmax over j (rows of S^T), base-2 domain
        #pragma unroll
        for (int q = 0; q < 2; ++q) {
            float p[4][4];
            float mx = -1e30f;
            #pragma unroll
            for (int mt = 0; mt < 4; ++mt)
                #pragma unroll
                for (int r = 0; r < 4; ++r) {
                    float s = sacc[mt][q][r] * SM_C;
                    if (16 * mt + 4 * lg + r >= NF) s = -1e30f;
                    p[mt][r] = s;
                    mx = fmaxf(mx, s);
                }
            mx = fmaxf(mx, __shfl_xor(mx, 16));
            mx = fmaxf(mx, __shfl_xor(mx, 32));
            float sum = 0.f;
            #pragma unroll
            for (int mt = 0; mt < 4; ++mt)
                #pragma unroll
                for (int r = 0; r < 4; ++r) {
                    float e = fexp2(p[mt][r] - mx);
                    p[mt][r] = e; sum += e;
                }
            sum += __shfl_xor(sum, 16);
            sum += __shfl_xor(sum, 32);
            const float ri = frcp(sum);
            unsigned short* Pb = h ? Qb : P0;
            #pragma unroll
            for (int mt = 0; mt < 4; ++mt) {
                float4v pv;
                pv.x = p[mt][0] * ri; pv.y = p[mt][1] * ri;
                pv.z = p[mt][2] * ri; pv.w = p[mt][3] * ri;
                st_pack4(Pb + (lm + 16 * (2 * fh + q)) * STR + 16 * mt + 4 * lg, pv);
            }
        }
        __syncthreads();  // P written

        // ---------------- PV (+R as C-init): wave owns f-tile w ----------------
        float4v oacc[4];
        #pragma unroll
        for (int c = 0; c < 4; ++c) oacc[c] = racc[c];
        #pragma unroll
        for (int hh = 0; hh < 2; ++hh) {
            const unsigned short* Pb = hh ? Qb : P0;
            short8 pf0 = *(const short8*)(Pb + (lm + 16 * w) * STR + 8 * lg);
            short8 pf1 = *(const short8*)(Pb + (lm + 16 * w) * STR + 8 * lg + 32);
            #pragma unroll
            for (int nt2 = 0; nt2 < 2; ++nt2) {
                const int c = 2 * hh + nt2;
                short8 vf0 = *(const short8*)(Vt + (32 * hh + 16 * nt2 + lm) * STR + 8 * lg);
                short8 vf1 = *(const short8*)(Vt + (32 * hh + 16 * nt2 + lm) * STR + 8 * lg + 32);
                oacc[c] = MFMA(pf0, vf0, oacc[c]);
                oacc[c] = MFMA(pf1, vf1, oacc[c]);
            }
        }

        // ---------------- relu + LayerNorm + store ----------------
        float gm[4], bt[4];
        #pragma unroll
        for (int c = 0; c < 4; ++c) {
            gm[c] = gam_g[dom * 64 + 16 * c + lm];
            bt[c] = bet_g[dom * 64 + 16 * c + lm];
        }
        #pragma unroll
        for (int r = 0; r < 4; ++r) {
            float v[4];
            #pragma unroll
            for (int c = 0; c < 4; ++c) v[c] = fmaxf(oacc[c][r], 0.f);
            float s1 = v[0] + v[1] + v[2] + v[3];
            float s2 = v[0]*v[0] + v[1]*v[1] + v[2]*v[2] + v[3]*v[3];
            #pragma unroll
            for (int msk = 1; msk < 16; msk <<= 1) {
                s1 += __shfl_xor(s1, msk);
                s2 += __shfl_xor(s2, msk);
            }
            const float mean = s1 * (1.f / 64.f);
            const float var  = s2 * (1.f / 64.f) - mean * mean;
            const float rs   = rsqrtf(var + LN_EPS);
            const int f = 4 * lg + r + 16 * w;
            if (f < NF) {
                float* op = out_g + (size_t)b * (NF * NE) + f * 64 + lm;
                #pragma unroll
                for (int c = 0; c < 4; ++c)
                    op[16 * c] = (v[c] - mean) * rs * gm[c] + bt[c];
            }
        }
    }
}

extern "C" void kernel_launch(void* const* d_in, const int* in_sizes, int n_in,
                              void* d_out, int out_size, void* d_ws, size_t ws_size,
                              hipStream_t stream) {
    const float* x   = (const float*)d_in[0];
    const int*   dom = (const int*)  d_in[1];
    const float* wq  = (const float*)d_in[2];
    const float* wk  = (const float*)d_in[3];
    const float* wv  = (const float*)d_in[4];
    const float* wr  = (const float*)d_in[5];
    const float* gam = (const float*)d_in[6];
    const float* bet = (const float*)d_in[7];
    unsigned short* ws = (unsigned short*)d_ws;
    float* out = (float*)d_out;

    hipLaunchKernelGGL(prep_weights, dim3(176), dim3(256), 0, stream, wq, wk, wv, wr, ws);
    hipLaunchKernelGGL(mdr_mfma, dim3(GRID), dim3(256), 0, stream,
                       x, dom, ws, gam, bet, out);
}

// Round 4
// 219.546 us; speedup vs baseline: 1.5283x; 1.5283x over previous
//
#include <hip/hip_runtime.h>
#include <hip/hip_bf16.h>

#define NB    8192
#define NF    50
#define NE    64
#define STR   72            // LDS row stride in bf16 elems (144 B)
#define GPB   4             // batch rows per block
#define GRID  (NB / GPB)

typedef __attribute__((ext_vector_type(8))) short short8;   // 8 x bf16 MFMA A/B frag
typedef __attribute__((ext_vector_type(4))) short short4v;  // 4 x bf16 packed store
typedef __attribute__((ext_vector_type(4))) float float4v;  // MFMA C/D frag

static constexpr float SM_C   = 0.25509667991878083f; // (1/sqrt(32)) * log2(e)
static constexpr float LN_EPS = 1e-6f;

#define MFMA(a, b, c) __builtin_amdgcn_mfma_f32_16x16x32_bf16((a), (b), (c), 0, 0, 0)

__device__ __forceinline__ unsigned short f2bf(float f) {
    return __bfloat16_as_ushort(__float2bfloat16(f));  // native RNE cvt
}

__device__ __forceinline__ void st_pack4(unsigned short* p, float4v v) {
    union { unsigned short u[4]; short4v s; } r;
    r.u[0] = f2bf(v.x); r.u[1] = f2bf(v.y); r.u[2] = f2bf(v.z); r.u[3] = f2bf(v.w);
    *(short4v*)p = r.s;   // ds_write_b64
}

__device__ __forceinline__ float fexp2(float x) {
#if __has_builtin(__builtin_amdgcn_exp2f)
    return __builtin_amdgcn_exp2f(x);
#else
    float r; asm("v_exp_f32 %0, %1" : "=v"(r) : "v"(x)); return r;
#endif
}

__device__ __forceinline__ float frcp(float x) {
#if __has_builtin(__builtin_amdgcn_rcpf)
    return __builtin_amdgcn_rcpf(x);
#else
    return 1.f / x;
#endif
}

// ---- prep: transpose all weights to bf16 [mat][o][e] = W[e][o] in d_ws ----
// slots 0..7 = Wq domains, 8 = Wk, 9 = Wv, 10 = Wr
__global__ void prep_weights(const float* __restrict__ wq, const float* __restrict__ wk,
                             const float* __restrict__ wv, const float* __restrict__ wr,
                             unsigned short* __restrict__ ws) {
    int i = blockIdx.x * 256 + threadIdx.x;
    if (i >= 11 * 4096) return;
    int m = i >> 12, t = i & 4095, o = t >> 6, e = t & 63;
    float v;
    if (m < 8)       v = wq[(m * 64 + e) * 64 + o];
    else if (m == 8) v = wk[e * 64 + o];
    else if (m == 9) v = wv[e * 64 + o];
    else             v = wr[e * 64 + o];
    ws[i] = f2bf(v);
}

__global__ __launch_bounds__(256, 4)
void mdr_mfma(const float* __restrict__ x_g, const int* __restrict__ dom_g,
              const unsigned short* __restrict__ ws,
              const float* __restrict__ gam_g, const float* __restrict__ bet_g,
              float* __restrict__ out_g) {
    __shared__ __align__(16) unsigned short L[5 * NE * STR];   // 46080 B
    unsigned short* xs = L;                 // x rowmajor [64][STR]
    unsigned short* Qb = L + NE * STR;      // Q rowmajor [f][e]   (later: P head 1)
    unsigned short* Kb = L + 2 * NE * STR;  // K rowmajor [f][e]
    unsigned short* Vt = L + 3 * NE * STR;  // V^T [e][f]
    unsigned short* P0 = L + 4 * NE * STR;  // P head 0

    const int tid = threadIdx.x;
    const int lm  = tid & 15;        // lane & 15
    const int lg  = (tid >> 4) & 3;  // lane >> 4 within wave
    const int w   = tid >> 6;        // wave 0..3

    for (int rr = 0; rr < GPB; ++rr) {
        const int b = blockIdx.x * GPB + rr;
        __syncthreads();  // prior iteration's LDS reads complete

        // ---------------- stage x (f32 -> bf16, rows >= NF zeroed) ----------------
        {
            const float* xb = x_g + (size_t)b * (NF * NE);
            #pragma unroll
            for (int it = 0; it < 4; ++it) {
                int s = tid + it * 256;          // 0..1023 : row = s>>4, c4 = s&15
                int r = s >> 4, c4 = s & 15;
                float4v v = {0.f, 0.f, 0.f, 0.f};
                if (r < NF) v = *(const float4v*)(xb + s * 4);
                st_pack4(xs + r * STR + c4 * 4, v);
            }
        }
        __syncthreads();
        const int dom = dom_g[b] - 1;

        // ---------------- x fragments (from LDS; cheap to re-read) ----------------
        short8 xf[4][2];
        #pragma unroll
        for (int t = 0; t < 4; ++t)
            #pragma unroll
            for (int ks = 0; ks < 2; ++ks)
                xf[t][ks] = *(const short8*)(xs + (lm + 16 * t) * STR + 8 * lg + 32 * ks);

        // ---------------- Q^T = Wq^T x^T  (write rowmajor Q) ----------------
        {
            const unsigned short* wq = ws + dom * 4096;
            short8 qw[4][2];
            #pragma unroll
            for (int mt = 0; mt < 4; ++mt)
                #pragma unroll
                for (int ks = 0; ks < 2; ++ks)
                    qw[mt][ks] = *(const short8*)(wq + (lm + 16 * mt) * 64 + 8 * lg + 32 * ks);
            #pragma unroll
            for (int mt = 0; mt < 4; ++mt) {
                float4v acc = {0.f, 0.f, 0.f, 0.f};
                acc = MFMA(qw[mt][0], xf[w][0], acc);
                acc = MFMA(qw[mt][1], xf[w][1], acc);
                st_pack4(Qb + (lm + 16 * w) * STR + 16 * mt + 4 * lg, acc);
            }
        }
        // ---------------- K^T = Wk^T x^T  (write rowmajor K) ----------------
        {
            const unsigned short* wk = ws + 8 * 4096;
            short8 kw[4][2];
            #pragma unroll
            for (int mt = 0; mt < 4; ++mt)
                #pragma unroll
                for (int ks = 0; ks < 2; ++ks)
                    kw[mt][ks] = *(const short8*)(wk + (lm + 16 * mt) * 64 + 8 * lg + 32 * ks);
            #pragma unroll
            for (int mt = 0; mt < 4; ++mt) {
                float4v acc = {0.f, 0.f, 0.f, 0.f};
                acc = MFMA(kw[mt][0], xf[w][0], acc);
                acc = MFMA(kw[mt][1], xf[w][1], acc);
                st_pack4(Kb + (lm + 16 * w) * STR + 16 * mt + 4 * lg, acc);
            }
        }
        // ---------------- V = x Wv  (write V^T [e][f]) ----------------
        {
            const unsigned short* wv = ws + 9 * 4096;
            short8 vw[2];
            #pragma unroll
            for (int ks = 0; ks < 2; ++ks)
                vw[ks] = *(const short8*)(wv + (lm + 16 * w) * 64 + 8 * lg + 32 * ks);
            #pragma unroll
            for (int mt = 0; mt < 4; ++mt) {
                float4v acc = {0.f, 0.f, 0.f, 0.f};
                acc = MFMA(xf[mt][0], vw[0], acc);
                acc = MFMA(xf[mt][1], vw[1], acc);
                st_pack4(Vt + (lm + 16 * w) * STR + 16 * mt + 4 * lg, acc);
            }
        }
        // ---------------- R = x Wr  (registers; wave owns f-tile w) ----------------
        float4v racc[4];
        {
            const unsigned short* wr = ws + 10 * 4096;
            #pragma unroll
            for (int nt = 0; nt < 4; ++nt) {
                short8 rw0 = *(const short8*)(wr + (lm + 16 * nt) * 64 + 8 * lg);
                short8 rw1 = *(const short8*)(wr + (lm + 16 * nt) * 64 + 8 * lg + 32);
                float4v acc = {0.f, 0.f, 0.f, 0.f};
                acc = MFMA(xf[w][0], rw0, acc);
                acc = MFMA(xf[w][1], rw1, acc);
                racc[nt] = acc;
            }
        }
        __syncthreads();  // Q/K/Vt written

        // ---------------- scores: wave -> (head h, f-half fh); S^T = K Q^T ----------------
        const int h = w & 1, fh = w >> 1;
        short8 kf[4], qf[2];
        #pragma unroll
        for (int mt = 0; mt < 4; ++mt)
            kf[mt] = *(const short8*)(Kb + (lm + 16 * mt) * STR + 32 * h + 8 * lg);
        #pragma unroll
        for (int q = 0; q < 2; ++q)
            qf[q] = *(const short8*)(Qb + (lm + 16 * (2 * fh + q)) * STR + 32 * h + 8 * lg);
        __syncthreads();  // frag loads done -> safe to overwrite Qb (P1)

        float4v sacc[4][2];
        #pragma unroll
        for (int mt = 0; mt < 4; ++mt)
            #pragma unroll
            for (int q = 0; q < 2; ++q) {
                float4v z = {0.f, 0.f, 0.f, 0.f};
                sacc[mt][q] = MFMA(kf[mt], qf[q], z);
            }

        // softmax over j (rows of S^T), base-2 domain
        #pragma unroll
        for (int q = 0; q < 2; ++q) {
            float p[4][4];
            float mx = -1e30f;
            #pragma unroll
            for (int mt = 0; mt < 4; ++mt)
                #pragma unroll
                for (int r = 0; r < 4; ++r) {
                    float s = sacc[mt][q][r] * SM_C;
                    if (16 * mt + 4 * lg + r >= NF) s = -1e30f;
                    p[mt][r] = s;
                    mx = fmaxf(mx, s);
                }
            mx = fmaxf(mx, __shfl_xor(mx, 16));
            mx = fmaxf(mx, __shfl_xor(mx, 32));
            float sum = 0.f;
            #pragma unroll
            for (int mt = 0; mt < 4; ++mt)
                #pragma unroll
                for (int r = 0; r < 4; ++r) {
                    float e = fexp2(p[mt][r] - mx);
                    p[mt][r] = e; sum += e;
                }
            sum += __shfl_xor(sum, 16);
            sum += __shfl_xor(sum, 32);
            const float ri = frcp(sum);
            unsigned short* Pb = h ? Qb : P0;
            #pragma unroll
            for (int mt = 0; mt < 4; ++mt) {
                float4v pv;
                pv.x = p[mt][0] * ri; pv.y = p[mt][1] * ri;
                pv.z = p[mt][2] * ri; pv.w = p[mt][3] * ri;
                st_pack4(Pb + (lm + 16 * (2 * fh + q)) * STR + 16 * mt + 4 * lg, pv);
            }
        }
        __syncthreads();  // P written

        // ---------------- PV (+R as C-init): wave owns f-tile w ----------------
        float4v oacc[4];
        #pragma unroll
        for (int c = 0; c < 4; ++c) oacc[c] = racc[c];
        #pragma unroll
        for (int hh = 0; hh < 2; ++hh) {
            const unsigned short* Pb = hh ? Qb : P0;
            short8 pf0 = *(const short8*)(Pb + (lm + 16 * w) * STR + 8 * lg);
            short8 pf1 = *(const short8*)(Pb + (lm + 16 * w) * STR + 8 * lg + 32);
            #pragma unroll
            for (int nt2 = 0; nt2 < 2; ++nt2) {
                const int c = 2 * hh + nt2;
                short8 vf0 = *(const short8*)(Vt + (32 * hh + 16 * nt2 + lm) * STR + 8 * lg);
                short8 vf1 = *(const short8*)(Vt + (32 * hh + 16 * nt2 + lm) * STR + 8 * lg + 32);
                oacc[c] = MFMA(pf0, vf0, oacc[c]);
                oacc[c] = MFMA(pf1, vf1, oacc[c]);
            }
        }

        // ---------------- relu + LayerNorm + store ----------------
        float gm[4], bt[4];
        #pragma unroll
        for (int c = 0; c < 4; ++c) {
            gm[c] = gam_g[dom * 64 + 16 * c + lm];
            bt[c] = bet_g[dom * 64 + 16 * c + lm];
        }
        #pragma unroll
        for (int r = 0; r < 4; ++r) {
            float v[4];
            #pragma unroll
            for (int c = 0; c < 4; ++c) v[c] = fmaxf(oacc[c][r], 0.f);
            float s1 = v[0] + v[1] + v[2] + v[3];
            float s2 = v[0]*v[0] + v[1]*v[1] + v[2]*v[2] + v[3]*v[3];
            #pragma unroll
            for (int msk = 1; msk < 16; msk <<= 1) {
                s1 += __shfl_xor(s1, msk);
                s2 += __shfl_xor(s2, msk);
            }
            const float mean = s1 * (1.f / 64.f);
            const float var  = s2 * (1.f / 64.f) - mean * mean;
            const float rs   = rsqrtf(var + LN_EPS);
            const int f = 4 * lg + r + 16 * w;
            if (f < NF) {
                float* op = out_g + (size_t)b * (NF * NE) + f * 64 + lm;
                #pragma unroll
                for (int c = 0; c < 4; ++c)
                    op[16 * c] = (v[c] - mean) * rs * gm[c] + bt[c];
            }
        }
    }
}

extern "C" void kernel_launch(void* const* d_in, const int* in_sizes, int n_in,
                              void* d_out, int out_size, void* d_ws, size_t ws_size,
                              hipStream_t stream) {
    const float* x   = (const float*)d_in[0];
    const int*   dom = (const int*)  d_in[1];
    const float* wq  = (const float*)d_in[2];
    const float* wk  = (const float*)d_in[3];
    const float* wv  = (const float*)d_in[4];
    const float* wr  = (const float*)d_in[5];
    const float* gam = (const float*)d_in[6];
    const float* bet = (const float*)d_in[7];
    unsigned short* ws = (unsigned short*)d_ws;
    float* out = (float*)d_out;

    hipLaunchKernelGGL(prep_weights, dim3(176), dim3(256), 0, stream, wq, wk, wv, wr, ws);
    hipLaunchKernelGGL(mdr_mfma, dim3(GRID), dim3(256), 0, stream,
                       x, dom, ws, gam, bet, out);
}

// Round 5
// 183.819 us; speedup vs baseline: 1.8254x; 1.1944x over previous
//
#include <hip/hip_runtime.h>
#include <hip/hip_bf16.h>

#define NB    8192
#define NF    50
#define NE    64
#define STR   72            // LDS row stride in bf16 elems (144 B)

typedef __attribute__((ext_vector_type(8))) short short8;   // 8 x bf16 MFMA A/B frag
typedef __attribute__((ext_vector_type(4))) short short4v;  // 4 x bf16 packed store
typedef __attribute__((ext_vector_type(4))) float float4v;  // MFMA C/D frag

static constexpr float SM_C   = 0.25509667991878083f; // (1/sqrt(32)) * log2(e), folded into Wk
static constexpr float LN_EPS = 1e-6f;

#define MFMA(a, b, c) __builtin_amdgcn_mfma_f32_16x16x32_bf16((a), (b), (c), 0, 0, 0)

__device__ __forceinline__ unsigned short f2bf(float f) {
    return __bfloat16_as_ushort(__float2bfloat16(f));  // native RNE cvt
}

__device__ __forceinline__ void st_pack4(unsigned short* p, float4v v) {
    union { unsigned short u[4]; short4v s; } r;
    r.u[0] = f2bf(v.x); r.u[1] = f2bf(v.y); r.u[2] = f2bf(v.z); r.u[3] = f2bf(v.w);
    *(short4v*)p = r.s;   // ds_write_b64
}

__device__ __forceinline__ float fexp2(float x) {
#if __has_builtin(__builtin_amdgcn_exp2f)
    return __builtin_amdgcn_exp2f(x);
#else
    float r; asm("v_exp_f32 %0, %1" : "=v"(r) : "v"(x)); return r;
#endif
}

__device__ __forceinline__ float frcp(float x) {
#if __has_builtin(__builtin_amdgcn_rcpf)
    return __builtin_amdgcn_rcpf(x);
#else
    return 1.f / x;
#endif
}

// ---- prep: transpose all weights to bf16 [mat][o][e] = W[e][o] in d_ws ----
// slots 0..7 = Wq domains, 8 = Wk (pre-scaled by SM_C), 9 = Wv, 10 = Wr
__global__ void prep_weights(const float* __restrict__ wq, const float* __restrict__ wk,
                             const float* __restrict__ wv, const float* __restrict__ wr,
                             unsigned short* __restrict__ ws) {
    int i = blockIdx.x * 256 + threadIdx.x;
    if (i >= 11 * 4096) return;
    int m = i >> 12, t = i & 4095, o = t >> 6, e = t & 63;
    float v;
    if (m < 8)       v = wq[(m * 64 + e) * 64 + o];
    else if (m == 8) v = wk[e * 64 + o] * SM_C;   // fold softmax scale (and log2e) into K
    else if (m == 9) v = wv[e * 64 + o];
    else             v = wr[e * 64 + o];
    ws[i] = f2bf(v);
}

__global__ __launch_bounds__(256, 3)
void mdr_mfma(const float* __restrict__ x_g, const int* __restrict__ dom_g,
              const unsigned short* __restrict__ ws,
              const float* __restrict__ gam_g, const float* __restrict__ bet_g,
              float* __restrict__ out_g) {
    __shared__ __align__(16) unsigned short L[5 * NE * STR];   // 46080 B -> 3 blocks/CU
    unsigned short* xs = L;                 // x rowmajor [64][STR]  (later: P head 1)
    unsigned short* Qb = L + NE * STR;      // Q rowmajor [f][e]
    unsigned short* Kb = L + 2 * NE * STR;  // K rowmajor [f][e] (pre-scaled)
    unsigned short* Vt = L + 3 * NE * STR;  // V^T [e][f]
    unsigned short* P0 = L + 4 * NE * STR;  // P head 0

    const int tid = threadIdx.x;
    const int lm  = tid & 15;        // lane & 15
    const int lg  = (tid >> 4) & 3;  // lane >> 4 within wave
    const int w   = tid >> 6;        // wave 0..3
    const int b   = blockIdx.x;

    const int dom = dom_g[b] - 1;

    // ---------------- stage x (f32 -> bf16, rows >= NF zeroed) ----------------
    {
        const float* xb = x_g + (size_t)b * (NF * NE);
        #pragma unroll
        for (int it = 0; it < 4; ++it) {
            int s = tid + it * 256;          // 0..1023 : row = s>>4, c4 = s&15
            int r = s >> 4, c4 = s & 15;
            float4v v = {0.f, 0.f, 0.f, 0.f};
            if (r < NF) v = *(const float4v*)(xb + s * 4);
            st_pack4(xs + r * STR + c4 * 4, v);
        }
    }
    __syncthreads();   // barrier 1: xs staged

    // ---------------- x fragments (from LDS) ----------------
    short8 xf[4][2];
    #pragma unroll
    for (int t = 0; t < 4; ++t)
        #pragma unroll
        for (int ks = 0; ks < 2; ++ks)
            xf[t][ks] = *(const short8*)(xs + (lm + 16 * t) * STR + 8 * lg + 32 * ks);

    // ---------------- Q^T = Wq^T x^T  (write rowmajor Q) ----------------
    {
        const unsigned short* wq = ws + dom * 4096;
        short8 qw[4][2];
        #pragma unroll
        for (int mt = 0; mt < 4; ++mt)
            #pragma unroll
            for (int ks = 0; ks < 2; ++ks)
                qw[mt][ks] = *(const short8*)(wq + (lm + 16 * mt) * 64 + 8 * lg + 32 * ks);
        #pragma unroll
        for (int mt = 0; mt < 4; ++mt) {
            float4v acc = {0.f, 0.f, 0.f, 0.f};
            acc = MFMA(qw[mt][0], xf[w][0], acc);
            acc = MFMA(qw[mt][1], xf[w][1], acc);
            st_pack4(Qb + (lm + 16 * w) * STR + 16 * mt + 4 * lg, acc);
        }
    }
    // ---------------- K^T = Wk^T x^T  (write rowmajor K; rows >= NF exactly 0) ----------------
    {
        const unsigned short* wk = ws + 8 * 4096;
        short8 kw[4][2];
        #pragma unroll
        for (int mt = 0; mt < 4; ++mt)
            #pragma unroll
            for (int ks = 0; ks < 2; ++ks)
                kw[mt][ks] = *(const short8*)(wk + (lm + 16 * mt) * 64 + 8 * lg + 32 * ks);
        #pragma unroll
        for (int mt = 0; mt < 4; ++mt) {
            float4v acc = {0.f, 0.f, 0.f, 0.f};
            acc = MFMA(kw[mt][0], xf[w][0], acc);
            acc = MFMA(kw[mt][1], xf[w][1], acc);
            st_pack4(Kb + (lm + 16 * w) * STR + 16 * mt + 4 * lg, acc);
        }
    }
    // ---------------- V = x Wv  (write V^T [e][f]; cols >= NF exactly 0) ----------------
    {
        const unsigned short* wv = ws + 9 * 4096;
        short8 vw[2];
        #pragma unroll
        for (int ks = 0; ks < 2; ++ks)
            vw[ks] = *(const short8*)(wv + (lm + 16 * w) * 64 + 8 * lg + 32 * ks);
        #pragma unroll
        for (int mt = 0; mt < 4; ++mt) {
            float4v acc = {0.f, 0.f, 0.f, 0.f};
            acc = MFMA(xf[mt][0], vw[0], acc);
            acc = MFMA(xf[mt][1], vw[1], acc);
            st_pack4(Vt + (lm + 16 * w) * STR + 16 * mt + 4 * lg, acc);
        }
    }
    // ---------------- R = x Wr  (registers; wave owns f-tile w) ----------------
    float4v racc[4];
    {
        const unsigned short* wr = ws + 10 * 4096;
        #pragma unroll
        for (int nt = 0; nt < 4; ++nt) {
            short8 rw0 = *(const short8*)(wr + (lm + 16 * nt) * 64 + 8 * lg);
            short8 rw1 = *(const short8*)(wr + (lm + 16 * nt) * 64 + 8 * lg + 32);
            float4v acc = {0.f, 0.f, 0.f, 0.f};
            acc = MFMA(xf[w][0], rw0, acc);
            acc = MFMA(xf[w][1], rw1, acc);
            racc[nt] = acc;
        }
    }
    __syncthreads();   // barrier 2: Q/K/Vt visible; xs dead (xf consumed)

    // ---------------- scores: wave -> (head h, f-half fh); S^T = K Q^T (pre-scaled) ----------------
    const int h = w & 1, fh = w >> 1;
    short8 kf[4], qf[2];
    #pragma unroll
    for (int mt = 0; mt < 4; ++mt)
        kf[mt] = *(const short8*)(Kb + (lm + 16 * mt) * STR + 32 * h + 8 * lg);
    #pragma unroll
    for (int q = 0; q < 2; ++q)
        qf[q] = *(const short8*)(Qb + (lm + 16 * (2 * fh + q)) * STR + 32 * h + 8 * lg);

    float4v sacc[4][2];
    #pragma unroll
    for (int mt = 0; mt < 4; ++mt)
        #pragma unroll
        for (int q = 0; q < 2; ++q) {
            float4v z = {0.f, 0.f, 0.f, 0.f};
            sacc[mt][q] = MFMA(kf[mt], qf[q], z);
        }

    // gamma/beta issued early to hide global latency under softmax/PV
    float gm[4], bt[4];
    #pragma unroll
    for (int c = 0; c < 4; ++c) {
        gm[c] = gam_g[dom * 64 + 16 * c + lm];
        bt[c] = bet_g[dom * 64 + 16 * c + lm];
    }

    // softmax over j (rows of S^T), base-2 domain.
    // Pad rows j in [50,64) have score EXACTLY 0 (K rows zero); no per-element
    // masking needed: mx >= 0 includes them, and each contributes 2^(-mx) to the
    // sum -> closed-form fixup sum -= 14*2^(-mx). Pad P values are harmless in
    // PV because V columns >= 50 are exactly 0.
    #pragma unroll
    for (int q = 0; q < 2; ++q) {
        float p[4][4];
        float mx = 0.f;   // pads guarantee max >= 0
        #pragma unroll
        for (int mt = 0; mt < 4; ++mt)
            #pragma unroll
            for (int r = 0; r < 4; ++r) {
                p[mt][r] = sacc[mt][q][r];
                mx = fmaxf(mx, p[mt][r]);
            }
        mx = fmaxf(mx, __shfl_xor(mx, 16));
        mx = fmaxf(mx, __shfl_xor(mx, 32));
        float sum = 0.f;
        #pragma unroll
        for (int mt = 0; mt < 4; ++mt)
            #pragma unroll
            for (int r = 0; r < 4; ++r) {
                float e = fexp2(p[mt][r] - mx);
                p[mt][r] = e; sum += e;
            }
        sum += __shfl_xor(sum, 16);
        sum += __shfl_xor(sum, 32);
        sum -= 14.f * fexp2(-mx);    // remove the 14 pad contributions
        const float ri = frcp(sum);
        unsigned short* Pb = h ? xs : P0;   // P head 1 overlays dead xs
        #pragma unroll
        for (int mt = 0; mt < 4; ++mt) {
            float4v pv;
            pv.x = p[mt][0] * ri; pv.y = p[mt][1] * ri;
            pv.z = p[mt][2] * ri; pv.w = p[mt][3] * ri;
            st_pack4(Pb + (lm + 16 * (2 * fh + q)) * STR + 16 * mt + 4 * lg, pv);
        }
    }
    __syncthreads();   // barrier 3: P visible

    // ---------------- PV (+R as C-init): wave owns f-tile w ----------------
    float4v oacc[4];
    #pragma unroll
    for (int c = 0; c < 4; ++c) oacc[c] = racc[c];
    #pragma unroll
    for (int hh = 0; hh < 2; ++hh) {
        const unsigned short* Pb = hh ? xs : P0;
        short8 pf0 = *(const short8*)(Pb + (lm + 16 * w) * STR + 8 * lg);
        short8 pf1 = *(const short8*)(Pb + (lm + 16 * w) * STR + 8 * lg + 32);
        #pragma unroll
        for (int nt2 = 0; nt2 < 2; ++nt2) {
            const int c = 2 * hh + nt2;
            short8 vf0 = *(const short8*)(Vt + (32 * hh + 16 * nt2 + lm) * STR + 8 * lg);
            short8 vf1 = *(const short8*)(Vt + (32 * hh + 16 * nt2 + lm) * STR + 8 * lg + 32);
            oacc[c] = MFMA(pf0, vf0, oacc[c]);
            oacc[c] = MFMA(pf1, vf1, oacc[c]);
        }
    }

    // ---------------- relu + LayerNorm + store (4 independent shfl chains) ----------------
    float v[4][4], s1[4], s2[4];
    #pragma unroll
    for (int r = 0; r < 4; ++r) {
        #pragma unroll
        for (int c = 0; c < 4; ++c) v[r][c] = fmaxf(oacc[c][r], 0.f);
        s1[r] = v[r][0] + v[r][1] + v[r][2] + v[r][3];
        s2[r] = v[r][0]*v[r][0] + v[r][1]*v[r][1] + v[r][2]*v[r][2] + v[r][3]*v[r][3];
    }
    #pragma unroll
    for (int msk = 1; msk < 16; msk <<= 1) {
        #pragma unroll
        for (int r = 0; r < 4; ++r) {
            s1[r] += __shfl_xor(s1[r], msk);
            s2[r] += __shfl_xor(s2[r], msk);
        }
    }
    #pragma unroll
    for (int r = 0; r < 4; ++r) {
        const float mean = s1[r] * (1.f / 64.f);
        const float var  = s2[r] * (1.f / 64.f) - mean * mean;
        const float rs   = rsqrtf(var + LN_EPS);
        const int f = 4 * lg + r + 16 * w;
        if (f < NF) {
            float* op = out_g + (size_t)b * (NF * NE) + f * 64 + lm;
            #pragma unroll
            for (int c = 0; c < 4; ++c)
                op[16 * c] = (v[r][c] - mean) * rs * gm[c] + bt[c];
        }
    }
}

extern "C" void kernel_launch(void* const* d_in, const int* in_sizes, int n_in,
                              void* d_out, int out_size, void* d_ws, size_t ws_size,
                              hipStream_t stream) {
    const float* x   = (const float*)d_in[0];
    const int*   dom = (const int*)  d_in[1];
    const float* wq  = (const float*)d_in[2];
    const float* wk  = (const float*)d_in[3];
    const float* wv  = (const float*)d_in[4];
    const float* wr  = (const float*)d_in[5];
    const float* gam = (const float*)d_in[6];
    const float* bet = (const float*)d_in[7];
    unsigned short* ws = (unsigned short*)d_ws;
    float* out = (float*)d_out;

    hipLaunchKernelGGL(prep_weights, dim3(176), dim3(256), 0, stream, wq, wk, wv, wr, ws);
    hipLaunchKernelGGL(mdr_mfma, dim3(NB), dim3(256), 0, stream,
                       x, dom, ws, gam, bet, out);
}

// Round 6
// 160.148 us; speedup vs baseline: 2.0952x; 1.1478x over previous
//
#include <hip/hip_runtime.h>
#include <hip/hip_bf16.h>

#define NB    8192
#define NF    50
#define NE    64
#define STR   72            // LDS row stride in bf16 elems (144 B)

typedef __attribute__((ext_vector_type(8))) short short8;   // 8 x bf16 MFMA A/B frag
typedef __attribute__((ext_vector_type(4))) short short4v;  // 4 x bf16 packed store
typedef __attribute__((ext_vector_type(4))) float float4v;  // MFMA C/D frag

static constexpr float SM_C   = 0.25509667991878083f; // (1/sqrt(32)) * log2(e), folded into Wk
static constexpr float LN_EPS = 1e-6f;

#define MFMA(a, b, c) __builtin_amdgcn_mfma_f32_16x16x32_bf16((a), (b), (c), 0, 0, 0)

__device__ __forceinline__ unsigned short f2bf(float f) {
    return __bfloat16_as_ushort(__float2bfloat16(f));  // native RNE cvt
}

__device__ __forceinline__ void st_pack4(unsigned short* p, float4v v) {
    union { unsigned short u[4]; short4v s; } r;
    r.u[0] = f2bf(v.x); r.u[1] = f2bf(v.y); r.u[2] = f2bf(v.z); r.u[3] = f2bf(v.w);
    *(short4v*)p = r.s;   // ds_write_b64
}

__device__ __forceinline__ float fexp2(float x) {
#if __has_builtin(__builtin_amdgcn_exp2f)
    return __builtin_amdgcn_exp2f(x);
#else
    float r; asm("v_exp_f32 %0, %1" : "=v"(r) : "v"(x)); return r;
#endif
}

__device__ __forceinline__ float frcp(float x) {
#if __has_builtin(__builtin_amdgcn_rcpf)
    return __builtin_amdgcn_rcpf(x);
#else
    return 1.f / x;
#endif
}

// ---- prep: transpose all weights to bf16 [mat][o][e] = W[e][o] in d_ws ----
// slots 0..7 = Wq domains, 8 = Wk (pre-scaled by SM_C), 9 = Wv, 10 = Wr
__global__ void prep_weights(const float* __restrict__ wq, const float* __restrict__ wk,
                             const float* __restrict__ wv, const float* __restrict__ wr,
                             unsigned short* __restrict__ ws) {
    int i = blockIdx.x * 256 + threadIdx.x;
    if (i >= 11 * 4096) return;
    int m = i >> 12, t = i & 4095, o = t >> 6, e = t & 63;
    float v;
    if (m < 8)       v = wq[(m * 64 + e) * 64 + o];
    else if (m == 8) v = wk[e * 64 + o] * SM_C;   // fold softmax scale (and log2e) into K
    else if (m == 9) v = wv[e * 64 + o];
    else             v = wr[e * 64 + o];
    ws[i] = f2bf(v);
}

__global__ __launch_bounds__(256, 4)
void mdr_mfma(const float* __restrict__ x_g, const int* __restrict__ dom_g,
              const unsigned short* __restrict__ ws,
              const float* __restrict__ gam_g, const float* __restrict__ bet_g,
              float* __restrict__ out_g) {
    __shared__ __align__(16) unsigned short L[4 * NE * STR];   // 36864 B -> 4 blocks/CU
    unsigned short* xs = L;                 // x rowmajor [64][STR]  (later: P head 1)
    unsigned short* Qb = L + NE * STR;      // Q rowmajor [f][e]
    unsigned short* Kb = L + 2 * NE * STR;  // K rowmajor [f][e]     (later: P head 0)
    unsigned short* Vt = L + 3 * NE * STR;  // V^T [e][f]
    unsigned short* P0 = Kb;                // P head 0 overlays K (dead after kf loads)
    unsigned short* P1 = xs;                // P head 1 overlays x  (dead after xf loads)

    const int tid = threadIdx.x;
    const int lm  = tid & 15;        // lane & 15
    const int lg  = (tid >> 4) & 3;  // lane >> 4 within wave
    const int w   = tid >> 6;        // wave 0..3
    const int b   = blockIdx.x;

    const int dom = dom_g[b] - 1;

    // ---------------- stage x (f32 -> bf16, rows >= NF zeroed) ----------------
    {
        const float* xb = x_g + (size_t)b * (NF * NE);
        #pragma unroll
        for (int it = 0; it < 4; ++it) {
            int s = tid + it * 256;          // 0..1023 : row = s>>4, c4 = s&15
            int r = s >> 4, c4 = s & 15;
            float4v v = {0.f, 0.f, 0.f, 0.f};
            if (r < NF) v = *(const float4v*)(xb + s * 4);
            st_pack4(xs + r * STR + c4 * 4, v);
        }
    }
    __syncthreads();   // barrier 1: xs staged

    // ---------------- x fragments (from LDS) ----------------
    short8 xf[4][2];
    #pragma unroll
    for (int t = 0; t < 4; ++t)
        #pragma unroll
        for (int ks = 0; ks < 2; ++ks)
            xf[t][ks] = *(const short8*)(xs + (lm + 16 * t) * STR + 8 * lg + 32 * ks);

    // ---------------- Q^T = Wq^T x^T  (write rowmajor Q) ----------------
    {
        const unsigned short* wq = ws + dom * 4096;
        short8 qw[4][2];
        #pragma unroll
        for (int mt = 0; mt < 4; ++mt)
            #pragma unroll
            for (int ks = 0; ks < 2; ++ks)
                qw[mt][ks] = *(const short8*)(wq + (lm + 16 * mt) * 64 + 8 * lg + 32 * ks);
        #pragma unroll
        for (int mt = 0; mt < 4; ++mt) {
            float4v acc = {0.f, 0.f, 0.f, 0.f};
            acc = MFMA(qw[mt][0], xf[w][0], acc);
            acc = MFMA(qw[mt][1], xf[w][1], acc);
            st_pack4(Qb + (lm + 16 * w) * STR + 16 * mt + 4 * lg, acc);
        }
    }
    // ---------------- K^T = Wk^T x^T  (write rowmajor K; rows >= NF exactly 0) ----------------
    {
        const unsigned short* wk = ws + 8 * 4096;
        short8 kw[4][2];
        #pragma unroll
        for (int mt = 0; mt < 4; ++mt)
            #pragma unroll
            for (int ks = 0; ks < 2; ++ks)
                kw[mt][ks] = *(const short8*)(wk + (lm + 16 * mt) * 64 + 8 * lg + 32 * ks);
        #pragma unroll
        for (int mt = 0; mt < 4; ++mt) {
            float4v acc = {0.f, 0.f, 0.f, 0.f};
            acc = MFMA(kw[mt][0], xf[w][0], acc);
            acc = MFMA(kw[mt][1], xf[w][1], acc);
            st_pack4(Kb + (lm + 16 * w) * STR + 16 * mt + 4 * lg, acc);
        }
    }
    // ---------------- V = x Wv  (write V^T [e][f]; cols >= NF exactly 0) ----------------
    {
        const unsigned short* wv = ws + 9 * 4096;
        short8 vw[2];
        #pragma unroll
        for (int ks = 0; ks < 2; ++ks)
            vw[ks] = *(const short8*)(wv + (lm + 16 * w) * 64 + 8 * lg + 32 * ks);
        #pragma unroll
        for (int mt = 0; mt < 4; ++mt) {
            float4v acc = {0.f, 0.f, 0.f, 0.f};
            acc = MFMA(xf[mt][0], vw[0], acc);
            acc = MFMA(xf[mt][1], vw[1], acc);
            st_pack4(Vt + (lm + 16 * w) * STR + 16 * mt + 4 * lg, acc);
        }
    }
    // ---------------- R = x Wr  (registers; wave owns f-tile w) ----------------
    float4v racc[4];
    {
        const unsigned short* wr = ws + 10 * 4096;
        #pragma unroll
        for (int nt = 0; nt < 4; ++nt) {
            short8 rw0 = *(const short8*)(wr + (lm + 16 * nt) * 64 + 8 * lg);
            short8 rw1 = *(const short8*)(wr + (lm + 16 * nt) * 64 + 8 * lg + 32);
            float4v acc = {0.f, 0.f, 0.f, 0.f};
            acc = MFMA(xf[w][0], rw0, acc);
            acc = MFMA(xf[w][1], rw1, acc);
            racc[nt] = acc;
        }
    }
    __syncthreads();   // barrier 2: Q/K/Vt visible; xs dead (xf consumed)

    // ---------------- scores: wave -> (head h, f-half fh); S^T = K Q^T (pre-scaled) ----------------
    const int h = w & 1, fh = w >> 1;
    short8 kf[4], qf[2];
    #pragma unroll
    for (int mt = 0; mt < 4; ++mt)
        kf[mt] = *(const short8*)(Kb + (lm + 16 * mt) * STR + 32 * h + 8 * lg);
    #pragma unroll
    for (int q = 0; q < 2; ++q)
        qf[q] = *(const short8*)(Qb + (lm + 16 * (2 * fh + q)) * STR + 32 * h + 8 * lg);
    __syncthreads();   // barrier 2.5: all K/Q frags in regs -> Kb/xs reusable for P

    float4v sacc[4][2];
    #pragma unroll
    for (int mt = 0; mt < 4; ++mt)
        #pragma unroll
        for (int q = 0; q < 2; ++q) {
            float4v z = {0.f, 0.f, 0.f, 0.f};
            sacc[mt][q] = MFMA(kf[mt], qf[q], z);
        }

    // gamma/beta issued early to hide global latency under softmax/PV
    float gm[4], bt[4];
    #pragma unroll
    for (int c = 0; c < 4; ++c) {
        gm[c] = gam_g[dom * 64 + 16 * c + lm];
        bt[c] = bet_g[dom * 64 + 16 * c + lm];
    }

    // softmax over j (rows of S^T), base-2 domain.
    // Pad rows j in [50,64) have score EXACTLY 0 (K rows zero); closed-form
    // fixup sum -= 14*2^(-mx). Pad P values harmless (V cols >= 50 are 0).
    #pragma unroll
    for (int q = 0; q < 2; ++q) {
        float p[4][4];
        float mx = 0.f;   // pads guarantee max >= 0
        #pragma unroll
        for (int mt = 0; mt < 4; ++mt)
            #pragma unroll
            for (int r = 0; r < 4; ++r) {
                p[mt][r] = sacc[mt][q][r];
                mx = fmaxf(mx, p[mt][r]);
            }
        mx = fmaxf(mx, __shfl_xor(mx, 16));
        mx = fmaxf(mx, __shfl_xor(mx, 32));
        float sum = 0.f;
        #pragma unroll
        for (int mt = 0; mt < 4; ++mt)
            #pragma unroll
            for (int r = 0; r < 4; ++r) {
                float e = fexp2(p[mt][r] - mx);
                p[mt][r] = e; sum += e;
            }
        sum += __shfl_xor(sum, 16);
        sum += __shfl_xor(sum, 32);
        sum -= 14.f * fexp2(-mx);    // remove the 14 pad contributions
        const float ri = frcp(sum);
        unsigned short* Pb = h ? P1 : P0;
        #pragma unroll
        for (int mt = 0; mt < 4; ++mt) {
            float4v pv;
            pv.x = p[mt][0] * ri; pv.y = p[mt][1] * ri;
            pv.z = p[mt][2] * ri; pv.w = p[mt][3] * ri;
            st_pack4(Pb + (lm + 16 * (2 * fh + q)) * STR + 16 * mt + 4 * lg, pv);
        }
    }
    __syncthreads();   // barrier 3: P visible

    // ---------------- PV (+R as C-init): wave owns f-tile w ----------------
    float4v oacc[4];
    #pragma unroll
    for (int c = 0; c < 4; ++c) oacc[c] = racc[c];
    #pragma unroll
    for (int hh = 0; hh < 2; ++hh) {
        const unsigned short* Pb = hh ? P1 : P0;
        short8 pf0 = *(const short8*)(Pb + (lm + 16 * w) * STR + 8 * lg);
        short8 pf1 = *(const short8*)(Pb + (lm + 16 * w) * STR + 8 * lg + 32);
        #pragma unroll
        for (int nt2 = 0; nt2 < 2; ++nt2) {
            const int c = 2 * hh + nt2;
            short8 vf0 = *(const short8*)(Vt + (32 * hh + 16 * nt2 + lm) * STR + 8 * lg);
            short8 vf1 = *(const short8*)(Vt + (32 * hh + 16 * nt2 + lm) * STR + 8 * lg + 32);
            oacc[c] = MFMA(pf0, vf0, oacc[c]);
            oacc[c] = MFMA(pf1, vf1, oacc[c]);
        }
    }

    // ---------------- relu + LayerNorm + store (4 independent shfl chains) ----------------
    float v[4][4], s1[4], s2[4];
    #pragma unroll
    for (int r = 0; r < 4; ++r) {
        #pragma unroll
        for (int c = 0; c < 4; ++c) v[r][c] = fmaxf(oacc[c][r], 0.f);
        s1[r] = v[r][0] + v[r][1] + v[r][2] + v[r][3];
        s2[r] = v[r][0]*v[r][0] + v[r][1]*v[r][1] + v[r][2]*v[r][2] + v[r][3]*v[r][3];
    }
    #pragma unroll
    for (int msk = 1; msk < 16; msk <<= 1) {
        #pragma unroll
        for (int r = 0; r < 4; ++r) {
            s1[r] += __shfl_xor(s1[r], msk);
            s2[r] += __shfl_xor(s2[r], msk);
        }
    }
    #pragma unroll
    for (int r = 0; r < 4; ++r) {
        const float mean = s1[r] * (1.f / 64.f);
        const float var  = s2[r] * (1.f / 64.f) - mean * mean;
        const float rs   = rsqrtf(var + LN_EPS);
        const int f = 4 * lg + r + 16 * w;
        if (f < NF) {
            float* op = out_g + (size_t)b * (NF * NE) + f * 64 + lm;
            #pragma unroll
            for (int c = 0; c < 4; ++c)
                op[16 * c] = (v[r][c] - mean) * rs * gm[c] + bt[c];
        }
    }
}

extern "C" void kernel_launch(void* const* d_in, const int* in_sizes, int n_in,
                              void* d_out, int out_size, void* d_ws, size_t ws_size,
                              hipStream_t stream) {
    const float* x   = (const float*)d_in[0];
    const int*   dom = (const int*)  d_in[1];
    const float* wq  = (const float*)d_in[2];
    const float* wk  = (const float*)d_in[3];
    const float* wv  = (const float*)d_in[4];
    const float* wr  = (const float*)d_in[5];
    const float* gam = (const float*)d_in[6];
    const float* bet = (const float*)d_in[7];
    unsigned short* ws = (unsigned short*)d_ws;
    float* out = (float*)d_out;

    hipLaunchKernelGGL(prep_weights, dim3(176), dim3(256), 0, stream, wq, wk, wv, wr, ws);
    hipLaunchKernelGGL(mdr_mfma, dim3(NB), dim3(256), 0, stream,
                       x, dom, ws, gam, bet, out);
}